// Round 4
// baseline (101.140 us; speedup 1.0000x reference)
//
#include <hip/hip_runtime.h>

// Chamfer loss: x,y (16, 4096, 3) fp32 -> scalar.
//
// d(x,y) = ||x||^2 + (||y||^2 - 2 x.y); min over y only needs
//   t = fma(-x0,2y0, fma(-x1,2y1, fma(-x2,2y2, ||y||^2)))
//
// Round-4 structure (from rocprof):
//  - The ~44 us fillBufferAligned is the harness poisoning the full 256 MiB
//    workspace in-stream: fixed floor, cannot overlap (it writes ws).
//  - Round-3 XPT=16 regressed -> reverted to the proven XPT=8 shape.
//  - NEW: y-values are wave-uniform, so they go to SGPRs via s_load instead
//    of LDS. A pack kernel writes (2y0,2y1,2y2,||y||^2) float4s; pass 1 reads
//    them through the scalar path (s_load_dwordx4): zero LDS, zero barriers,
//    v_fma takes the SGPR operand directly (one v_mov per y for the ||y||^2
//    seed, amortized over 8 x-points -> 3.63 VALU/pair, ~13 us issue floor).
//  - Manual 2-y prefetch keeps one iteration of s_loads in flight.
//
// ws layout: [0, 8MB) = partial mins (16 x 32 x 4096 f32);
//            [8MB, 9MB) = packed y (16 x 4096 float4).

constexpr int NPTS   = 4096;
constexpr int NBATCH = 16;
constexpr int BLOCK  = 256;
constexpr int XPT    = 8;                    // x-points per thread
constexpr int XCHUNK = BLOCK * XPT;          // 2048
constexpr int NXC    = NPTS / XCHUNK;        // 2

constexpr int NYC32  = 32;
constexpr int YT32   = NPTS / NYC32;         // 128 y per block

// ---------------- pack: (2y0, 2y1, 2y2, ||y||^2) ---------------------------

__global__ __launch_bounds__(BLOCK) void chamfer_pack_kernel(
    const float* __restrict__ y, float4* __restrict__ pws)
{
    const int idx = blockIdx.x * BLOCK + threadIdx.x;   // 0 .. 16*4096-1
    const float* yp = y + (size_t)idx * 3;
    const float y0 = yp[0], y1 = yp[1], y2 = yp[2];
    pws[idx] = make_float4(2.0f * y0, 2.0f * y1, 2.0f * y2,
                           fmaf(y2, y2, fmaf(y1, y1, y0 * y0)));
}

// ---------------- pass 1: SGPR-y partial mins ------------------------------

__global__ __launch_bounds__(BLOCK, 4) void chamfer_part_sgpr_kernel(
    const float* __restrict__ x, const float4* __restrict__ pws,
    float* __restrict__ ws)
{
    const int b      = blockIdx.x / (NXC * NYC32);
    const int xchunk = (blockIdx.x / NYC32) % NXC;
    const int ychunk = blockIdx.x % NYC32;

    // This thread's 8 consecutive x-points (24 floats = 6 float4).
    const int xbase = xchunk * XCHUNK + threadIdx.x * XPT;
    const float4* xp4 = (const float4*)(x + ((size_t)b * NPTS + xbase) * 3);
    const float4 a0 = xp4[0], a1 = xp4[1], a2 = xp4[2];
    const float4 a3 = xp4[3], a4 = xp4[4], a5 = xp4[5];
    const float xa[XPT][3] = {
        {a0.x, a0.y, a0.z}, {a0.w, a1.x, a1.y},
        {a1.z, a1.w, a2.x}, {a2.y, a2.z, a2.w},
        {a3.x, a3.y, a3.z}, {a3.w, a4.x, a4.y},
        {a4.z, a4.w, a5.x}, {a5.y, a5.z, a5.w}};

    float m[XPT];
    #pragma unroll
    for (int i = 0; i < XPT; ++i) m[i] = 3.4e38f;

    // Wave-uniform y reads -> s_load_dwordx4 (scalar path, no LDS/barrier).
    const float4* yq = pws + (size_t)b * NPTS + ychunk * YT32;

    auto body = [&](const float4& Ya, const float4& Yb) {
        const float ynA = Ya.w;              // v_mov: seed must be VGPR
        const float ynB = Yb.w;              // (1 SGPR operand per v_fma)
        #pragma unroll
        for (int i = 0; i < XPT; ++i) {
            const float t0 = fmaf(-xa[i][0], Ya.x,
                             fmaf(-xa[i][1], Ya.y,
                             fmaf(-xa[i][2], Ya.z, ynA)));
            const float t1 = fmaf(-xa[i][0], Yb.x,
                             fmaf(-xa[i][1], Yb.y,
                             fmaf(-xa[i][2], Yb.z, ynB)));
            m[i] = fminf(fminf(t0, t1), m[i]);   // -> v_min3_f32
        }
    };

    float4 Ya = yq[0], Yb = yq[1];
    #pragma unroll 2
    for (int j = 0; j < YT32 - 2; j += 2) {
        const float4 Yc = yq[j + 2];         // prefetch next pair
        const float4 Yd = yq[j + 3];
        body(Ya, Yb);
        Ya = Yc; Yb = Yd;
    }
    body(Ya, Yb);

    // d = max(||x||^2 + min_t, 0); ||x||^2 recomputed in the epilogue.
    float* wp = ws + ((size_t)b * NYC32 + ychunk) * NPTS + xbase;
    #pragma unroll
    for (int i = 0; i < XPT; i += 4) {
        float4 o;
        float* oc = (float*)&o;
        #pragma unroll
        for (int k = 0; k < 4; ++k) {
            const int p = i + k;
            const float x2 = fmaf(xa[p][2], xa[p][2],
                             fmaf(xa[p][1], xa[p][1],
                                  xa[p][0] * xa[p][0]));
            oc[k] = fmaxf(x2 + m[p], 0.0f);
        }
        ((float4*)wp)[i / 4] = o;
    }
}

// ---------------- pass 2: min over ychunks, then sum -----------------------

template <int NYC>
__global__ __launch_bounds__(BLOCK) void chamfer_reduce_kernel(
    const float* __restrict__ ws, float* __restrict__ out)
{
    __shared__ float swsum[BLOCK / 64];
    const int idx = blockIdx.x * BLOCK + threadIdx.x;   // one x-point each
    const int b   = idx / NPTS;
    const int xp  = idx % NPTS;

    float mn = 3.4e38f;
    #pragma unroll 8
    for (int yc = 0; yc < NYC; ++yc)
        mn = fminf(mn, ws[((size_t)b * NYC + yc) * NPTS + xp]);

    float s = mn;
    for (int off = 32; off > 0; off >>= 1)
        s += __shfl_down(s, off, 64);
    const int wave = threadIdx.x >> 6;
    if ((threadIdx.x & 63) == 0) swsum[wave] = s;
    __syncthreads();
    if (threadIdx.x == 0) {
        float t = 0.f;
        #pragma unroll
        for (int w = 0; w < BLOCK / 64; ++w) t += swsum[w];
        atomicAdd(out, t * (1.0f / NPTS));
    }
}

// ---------------- fallback A: round-2 LDS store path (NYC=16) --------------

template <int NYC>
__global__ __launch_bounds__(BLOCK, 4) void chamfer_part_lds_kernel(
    const float* __restrict__ x, const float* __restrict__ y,
    float* __restrict__ ws)
{
    constexpr int YTILE = NPTS / NYC;
    __shared__ float4 sy[YTILE];

    const int b      = blockIdx.x / (NXC * NYC);
    const int xchunk = (blockIdx.x / NYC) % NXC;
    const int ychunk = blockIdx.x % NYC;

    for (int i = threadIdx.x; i < YTILE; i += BLOCK) {
        const float* yp = y + ((size_t)b * NPTS + ychunk * YTILE + i) * 3;
        const float y0 = yp[0], y1 = yp[1], y2 = yp[2];
        sy[i] = make_float4(2.0f * y0, 2.0f * y1, 2.0f * y2,
                            fmaf(y2, y2, fmaf(y1, y1, y0 * y0)));
    }

    const int xbase = xchunk * XCHUNK + threadIdx.x * XPT;
    const float4* xp4 = (const float4*)(x + ((size_t)b * NPTS + xbase) * 3);
    const float4 a0 = xp4[0], a1 = xp4[1], a2 = xp4[2];
    const float4 a3 = xp4[3], a4 = xp4[4], a5 = xp4[5];
    const float xa[XPT][3] = {
        {a0.x, a0.y, a0.z}, {a0.w, a1.x, a1.y},
        {a1.z, a1.w, a2.x}, {a2.y, a2.z, a2.w},
        {a3.x, a3.y, a3.z}, {a3.w, a4.x, a4.y},
        {a4.z, a4.w, a5.x}, {a5.y, a5.z, a5.w}};

    float x2s[XPT];
    #pragma unroll
    for (int i = 0; i < XPT; ++i)
        x2s[i] = fmaf(xa[i][2], xa[i][2],
                 fmaf(xa[i][1], xa[i][1], xa[i][0] * xa[i][0]));

    __syncthreads();

    float m[XPT];
    #pragma unroll
    for (int i = 0; i < XPT; ++i) m[i] = 3.4e38f;

    #pragma unroll 2
    for (int j = 0; j < YTILE; j += 2) {
        const float4 Y0 = sy[j];
        const float4 Y1 = sy[j + 1];
        #pragma unroll
        for (int i = 0; i < XPT; ++i) {
            const float t0 = fmaf(-xa[i][0], Y0.x,
                             fmaf(-xa[i][1], Y0.y,
                             fmaf(-xa[i][2], Y0.z, Y0.w)));
            const float t1 = fmaf(-xa[i][0], Y1.x,
                             fmaf(-xa[i][1], Y1.y,
                             fmaf(-xa[i][2], Y1.z, Y1.w)));
            m[i] = fminf(fminf(t0, t1), m[i]);
        }
    }

    float* wp = ws + ((size_t)b * NYC + ychunk) * NPTS + xbase;
    #pragma unroll
    for (int i = 0; i < XPT; i += 4) {
        float4 o;
        float* oc = (float*)&o;
        #pragma unroll
        for (int k = 0; k < 4; ++k)
            oc[k] = fmaxf(x2s[i + k] + m[i + k], 0.0f);
        ((float4*)wp)[i / 4] = o;
    }
}

// ---------------- fallback B: atomic path (tiny ws) ------------------------

__global__ __launch_bounds__(BLOCK) void chamfer_min_atomic_kernel(
    const float* __restrict__ x, const float* __restrict__ y,
    unsigned int* __restrict__ ws_min)
{
    constexpr int YTILE = 256;
    constexpr int NYC   = NPTS / YTILE;
    __shared__ float4 sy[YTILE];

    const int b      = blockIdx.x / (NXC * NYC);
    const int xchunk = (blockIdx.x / NYC) % NXC;
    const int ychunk = blockIdx.x % NYC;

    {
        const float* yp = y + ((size_t)b * NPTS + ychunk * YTILE + threadIdx.x) * 3;
        const float y0 = yp[0], y1 = yp[1], y2 = yp[2];
        sy[threadIdx.x] = make_float4(2.0f * y0, 2.0f * y1, 2.0f * y2,
                                      fmaf(y2, y2, fmaf(y1, y1, y0 * y0)));
    }

    const int xbase = xchunk * XCHUNK + threadIdx.x * XPT;
    const float4* xp4 = (const float4*)(x + ((size_t)b * NPTS + xbase) * 3);
    const float4 a0 = xp4[0], a1 = xp4[1], a2 = xp4[2];
    const float4 a3 = xp4[3], a4 = xp4[4], a5 = xp4[5];
    const float xa[XPT][3] = {
        {a0.x, a0.y, a0.z}, {a0.w, a1.x, a1.y},
        {a1.z, a1.w, a2.x}, {a2.y, a2.z, a2.w},
        {a3.x, a3.y, a3.z}, {a3.w, a4.x, a4.y},
        {a4.z, a4.w, a5.x}, {a5.y, a5.z, a5.w}};

    float x2s[XPT];
    #pragma unroll
    for (int i = 0; i < XPT; ++i)
        x2s[i] = fmaf(xa[i][2], xa[i][2],
                 fmaf(xa[i][1], xa[i][1], xa[i][0] * xa[i][0]));

    __syncthreads();

    float m[XPT];
    #pragma unroll
    for (int i = 0; i < XPT; ++i) m[i] = 3.4e38f;

    #pragma unroll 2
    for (int j = 0; j < YTILE; j += 2) {
        const float4 Y0 = sy[j];
        const float4 Y1 = sy[j + 1];
        #pragma unroll
        for (int i = 0; i < XPT; ++i) {
            const float t0 = fmaf(-xa[i][0], Y0.x,
                             fmaf(-xa[i][1], Y0.y,
                             fmaf(-xa[i][2], Y0.z, Y0.w)));
            const float t1 = fmaf(-xa[i][0], Y1.x,
                             fmaf(-xa[i][1], Y1.y,
                             fmaf(-xa[i][2], Y1.z, Y1.w)));
            m[i] = fminf(m[i], fminf(t0, t1));
        }
    }

    unsigned int* wm = ws_min + (size_t)b * NPTS + xbase;
    #pragma unroll
    for (int i = 0; i < XPT; ++i) {
        const float d = fmaxf(x2s[i] + m[i], 0.0f);
        atomicMin(&wm[i], __float_as_uint(d));
    }
}

__global__ __launch_bounds__(BLOCK) void chamfer_sum_kernel(
    const unsigned int* __restrict__ ws_min, float* __restrict__ out)
{
    __shared__ float swsum[BLOCK / 64];
    const int total = NBATCH * NPTS;
    float s = 0.f;
    for (int i = blockIdx.x * BLOCK + threadIdx.x; i < total;
         i += gridDim.x * BLOCK)
        s += __uint_as_float(ws_min[i]);

    for (int off = 32; off > 0; off >>= 1)
        s += __shfl_down(s, off, 64);
    const int wave = threadIdx.x >> 6;
    if ((threadIdx.x & 63) == 0) swsum[wave] = s;
    __syncthreads();
    if (threadIdx.x == 0) {
        float t = 0.f;
        #pragma unroll
        for (int w = 0; w < BLOCK / 64; ++w) t += swsum[w];
        atomicAdd(out, t * (1.0f / NPTS));
    }
}

// ---------------- host ------------------------------------------------------

extern "C" void kernel_launch(void* const* d_in, const int* in_sizes, int n_in,
                              void* d_out, int out_size, void* d_ws, size_t ws_size,
                              hipStream_t stream) {
    const float* x = (const float*)d_in[0];
    const float* y = (const float*)d_in[1];
    float* out = (float*)d_out;

    hipMemsetAsync(out, 0, sizeof(float), stream);

    const size_t part_bytes = (size_t)NBATCH * NYC32 * NPTS * sizeof(float); // 8 MB
    const size_t pack_bytes = (size_t)NBATCH * NPTS * sizeof(float4);        // 1 MB
    const size_t need_main  = part_bytes + pack_bytes;                       // 9 MB
    const size_t need16     = (size_t)NBATCH * 16 * NPTS * sizeof(float);    // 4 MB

    if (ws_size >= need_main) {
        float*  ws  = (float*)d_ws;
        float4* pws = (float4*)((char*)d_ws + part_bytes);
        chamfer_pack_kernel<<<NBATCH * NPTS / BLOCK, BLOCK, 0, stream>>>(y, pws);
        chamfer_part_sgpr_kernel<<<NBATCH * NXC * NYC32, BLOCK, 0, stream>>>(
            x, pws, ws);
        chamfer_reduce_kernel<NYC32><<<NBATCH * NPTS / BLOCK, BLOCK, 0, stream>>>(
            ws, out);
    } else if (ws_size >= need16) {
        float* ws = (float*)d_ws;
        chamfer_part_lds_kernel<16><<<NBATCH * NXC * 16, BLOCK, 0, stream>>>(
            x, y, ws);
        chamfer_reduce_kernel<16><<<NBATCH * NPTS / BLOCK, BLOCK, 0, stream>>>(
            ws, out);
    } else {
        unsigned int* ws_min = (unsigned int*)d_ws;
        hipMemsetAsync(ws_min, 0xFF, (size_t)NBATCH * NPTS * sizeof(unsigned int),
                       stream);
        chamfer_min_atomic_kernel<<<NBATCH * NXC * 16, BLOCK, 0, stream>>>(
            x, y, ws_min);
        chamfer_sum_kernel<<<64, BLOCK, 0, stream>>>(ws_min, out);
    }
}

// Round 5
// 97.427 us; speedup vs baseline: 1.0381x; 1.0381x over previous
//
#include <hip/hip_runtime.h>

// Chamfer loss: x,y (16, 4096, 3) fp32 -> scalar.
//
// d(x,y) = ||x||^2 + (||y||^2 - 2 x.y); min over y only needs
//   t = fma(-x0,2y0, fma(-x1,2y1, fma(-x2,2y2, ||y||^2)))
// with (2y0,2y1,2y2,||y||^2) packed per y-point at LDS-staging time.
// 3 FMA + 0.5 min3 per pair -> ~12 us VALU-issue floor for 268M pairs.
//
// Round-5 (from rocprof across rounds 1-4):
//  - Budget: harness ws-poison fill ~43 us (fixed, in-stream) + part + tail.
//  - Round-4 SGPR-y path regressed (pack kernel + no part gain) -> reverted
//    to the proven round-2 LDS structure.
//  - Round-1 VALUBusy was 55% at 2 waves/SIMD; round 2 ran 4 waves/SIMD.
//    Remaining gap is latency hiding -> target 8 waves/SIMD:
//      __launch_bounds__(256, 8) caps VGPR at 64 (loop needs ~48 live;
//      round 1 proved this loop fits in 32), NYC=64 -> 2048 blocks =
//      8 blocks/CU. #pragma unroll 1 on the y-loop keeps Y regs at one pair.
//  - ws: 16*64*4096 partial floats (16.8 MB); atomic path kept for tiny ws.

constexpr int NPTS   = 4096;
constexpr int NBATCH = 16;
constexpr int BLOCK  = 256;
constexpr int XPT    = 8;                    // x-points per thread
constexpr int XCHUNK = BLOCK * XPT;          // 2048
constexpr int NXC    = NPTS / XCHUNK;        // 2
constexpr int NYC    = 64;                   // y-chunks
constexpr int YT     = NPTS / NYC;           // 64 y-points per block (1 KB LDS)

// ---------------- pass 1: partial mins, 8 waves/SIMD -----------------------

__global__ __launch_bounds__(BLOCK, 8) void chamfer_part_kernel(
    const float* __restrict__ x, const float* __restrict__ y,
    float* __restrict__ ws)
{
    __shared__ float4 sy[YT];                // (2y0, 2y1, 2y2, ||y||^2)

    const int b      = blockIdx.x / (NXC * NYC);
    const int xchunk = (blockIdx.x / NYC) % NXC;
    const int ychunk = blockIdx.x % NYC;

    if (threadIdx.x < YT) {
        const float* yp = y + ((size_t)b * NPTS + ychunk * YT + threadIdx.x) * 3;
        const float y0 = yp[0], y1 = yp[1], y2 = yp[2];
        sy[threadIdx.x] = make_float4(2.0f * y0, 2.0f * y1, 2.0f * y2,
                                      fmaf(y2, y2, fmaf(y1, y1, y0 * y0)));
    }

    // This thread's 8 consecutive x-points (24 floats = 6 float4).
    const int xbase = xchunk * XCHUNK + threadIdx.x * XPT;
    const float4* xp4 = (const float4*)(x + ((size_t)b * NPTS + xbase) * 3);
    float xf[24];                            // xf[3*i+c] = coord c of x-point i
    #pragma unroll
    for (int q = 0; q < 6; ++q) {
        const float4 a = xp4[q];
        xf[4 * q + 0] = a.x; xf[4 * q + 1] = a.y;
        xf[4 * q + 2] = a.z; xf[4 * q + 3] = a.w;
    }

    __syncthreads();

    float m[XPT];
    #pragma unroll
    for (int i = 0; i < XPT; ++i) m[i] = 3.4e38f;

    #pragma unroll 1
    for (int j = 0; j < YT; j += 2) {
        const float4 Y0 = sy[j];
        const float4 Y1 = sy[j + 1];
        #pragma unroll
        for (int i = 0; i < XPT; ++i) {
            const float t0 = fmaf(-xf[3 * i + 0], Y0.x,
                             fmaf(-xf[3 * i + 1], Y0.y,
                             fmaf(-xf[3 * i + 2], Y0.z, Y0.w)));
            const float t1 = fmaf(-xf[3 * i + 0], Y1.x,
                             fmaf(-xf[3 * i + 1], Y1.y,
                             fmaf(-xf[3 * i + 2], Y1.z, Y1.w)));
            m[i] = fminf(fminf(t0, t1), m[i]);   // -> v_min3_f32
        }
    }

    // d = max(||x||^2 + min_t, 0); ||x||^2 recomputed here (not held live).
    float* wp = ws + ((size_t)b * NYC + ychunk) * NPTS + xbase;
    #pragma unroll
    for (int i = 0; i < XPT; i += 4) {
        float4 o;
        float* oc = (float*)&o;
        #pragma unroll
        for (int k = 0; k < 4; ++k) {
            const int p = i + k;
            const float x2 = fmaf(xf[3 * p + 2], xf[3 * p + 2],
                             fmaf(xf[3 * p + 1], xf[3 * p + 1],
                                  xf[3 * p + 0] * xf[3 * p + 0]));
            oc[k] = fmaxf(x2 + m[p], 0.0f);
        }
        ((float4*)wp)[i / 4] = o;
    }
}

// ---------------- pass 2: min over ychunks, then sum -----------------------

__global__ __launch_bounds__(BLOCK) void chamfer_reduce_kernel(
    const float* __restrict__ ws, float* __restrict__ out)
{
    __shared__ float swsum[BLOCK / 64];
    const int idx = blockIdx.x * BLOCK + threadIdx.x;   // one x-point each
    const int b   = idx / NPTS;
    const int xp  = idx % NPTS;

    const float* p = ws + (size_t)b * NYC * NPTS + xp;
    float mn = 3.4e38f;
    #pragma unroll 8
    for (int yc = 0; yc < NYC; ++yc)
        mn = fminf(mn, p[(size_t)yc * NPTS]);

    float s = mn;
    for (int off = 32; off > 0; off >>= 1)
        s += __shfl_down(s, off, 64);
    const int wave = threadIdx.x >> 6;
    if ((threadIdx.x & 63) == 0) swsum[wave] = s;
    __syncthreads();
    if (threadIdx.x == 0) {
        float t = 0.f;
        #pragma unroll
        for (int w = 0; w < BLOCK / 64; ++w) t += swsum[w];
        atomicAdd(out, t * (1.0f / NPTS));
    }
}

// ---------------- fallback: atomic path (tiny ws) --------------------------

__global__ __launch_bounds__(BLOCK) void chamfer_min_atomic_kernel(
    const float* __restrict__ x, const float* __restrict__ y,
    unsigned int* __restrict__ ws_min)
{
    constexpr int YTILE = 256;
    constexpr int FNYC  = NPTS / YTILE;
    __shared__ float4 sy[YTILE];

    const int b      = blockIdx.x / (NXC * FNYC);
    const int xchunk = (blockIdx.x / FNYC) % NXC;
    const int ychunk = blockIdx.x % FNYC;

    {
        const float* yp = y + ((size_t)b * NPTS + ychunk * YTILE + threadIdx.x) * 3;
        const float y0 = yp[0], y1 = yp[1], y2 = yp[2];
        sy[threadIdx.x] = make_float4(2.0f * y0, 2.0f * y1, 2.0f * y2,
                                      fmaf(y2, y2, fmaf(y1, y1, y0 * y0)));
    }

    const int xbase = xchunk * XCHUNK + threadIdx.x * XPT;
    const float4* xp4 = (const float4*)(x + ((size_t)b * NPTS + xbase) * 3);
    float xf[24];
    #pragma unroll
    for (int q = 0; q < 6; ++q) {
        const float4 a = xp4[q];
        xf[4 * q + 0] = a.x; xf[4 * q + 1] = a.y;
        xf[4 * q + 2] = a.z; xf[4 * q + 3] = a.w;
    }

    __syncthreads();

    float m[XPT];
    #pragma unroll
    for (int i = 0; i < XPT; ++i) m[i] = 3.4e38f;

    #pragma unroll 1
    for (int j = 0; j < YTILE; j += 2) {
        const float4 Y0 = sy[j];
        const float4 Y1 = sy[j + 1];
        #pragma unroll
        for (int i = 0; i < XPT; ++i) {
            const float t0 = fmaf(-xf[3 * i + 0], Y0.x,
                             fmaf(-xf[3 * i + 1], Y0.y,
                             fmaf(-xf[3 * i + 2], Y0.z, Y0.w)));
            const float t1 = fmaf(-xf[3 * i + 0], Y1.x,
                             fmaf(-xf[3 * i + 1], Y1.y,
                             fmaf(-xf[3 * i + 2], Y1.z, Y1.w)));
            m[i] = fminf(m[i], fminf(t0, t1));
        }
    }

    unsigned int* wm = ws_min + (size_t)b * NPTS + xbase;
    #pragma unroll
    for (int i = 0; i < XPT; ++i) {
        const float x2 = fmaf(xf[3 * i + 2], xf[3 * i + 2],
                         fmaf(xf[3 * i + 1], xf[3 * i + 1],
                              xf[3 * i + 0] * xf[3 * i + 0]));
        const float d = fmaxf(x2 + m[i], 0.0f);
        atomicMin(&wm[i], __float_as_uint(d));
    }
}

__global__ __launch_bounds__(BLOCK) void chamfer_sum_kernel(
    const unsigned int* __restrict__ ws_min, float* __restrict__ out)
{
    __shared__ float swsum[BLOCK / 64];
    const int total = NBATCH * NPTS;
    float s = 0.f;
    for (int i = blockIdx.x * BLOCK + threadIdx.x; i < total;
         i += gridDim.x * BLOCK)
        s += __uint_as_float(ws_min[i]);

    for (int off = 32; off > 0; off >>= 1)
        s += __shfl_down(s, off, 64);
    const int wave = threadIdx.x >> 6;
    if ((threadIdx.x & 63) == 0) swsum[wave] = s;
    __syncthreads();
    if (threadIdx.x == 0) {
        float t = 0.f;
        #pragma unroll
        for (int w = 0; w < BLOCK / 64; ++w) t += swsum[w];
        atomicAdd(out, t * (1.0f / NPTS));
    }
}

// ---------------- host ------------------------------------------------------

extern "C" void kernel_launch(void* const* d_in, const int* in_sizes, int n_in,
                              void* d_out, int out_size, void* d_ws, size_t ws_size,
                              hipStream_t stream) {
    const float* x = (const float*)d_in[0];
    const float* y = (const float*)d_in[1];
    float* out = (float*)d_out;

    hipMemsetAsync(out, 0, sizeof(float), stream);

    const size_t need = (size_t)NBATCH * NYC * NPTS * sizeof(float); // 16.8 MB

    if (ws_size >= need) {
        float* ws = (float*)d_ws;
        chamfer_part_kernel<<<NBATCH * NXC * NYC, BLOCK, 0, stream>>>(x, y, ws);
        chamfer_reduce_kernel<<<NBATCH * NPTS / BLOCK, BLOCK, 0, stream>>>(ws, out);
    } else {
        unsigned int* ws_min = (unsigned int*)d_ws;
        hipMemsetAsync(ws_min, 0xFF, (size_t)NBATCH * NPTS * sizeof(unsigned int),
                       stream);
        chamfer_min_atomic_kernel<<<NBATCH * NXC * 16, BLOCK, 0, stream>>>(
            x, y, ws_min);
        chamfer_sum_kernel<<<64, BLOCK, 0, stream>>>(ws_min, out);
    }
}